// Round 1
// baseline (127.560 us; speedup 1.0000x reference)
//
#include <hip/hip_runtime.h>
#include <math.h>

#define NEGV -9e15f

__device__ __forceinline__ float lrelu(float z){ return z > 0.f ? z : 0.5f*z; }
__device__ __forceinline__ float sigm(float z){ return 1.f/(1.f + __expf(-z)); }
__device__ __forceinline__ float reluf(float z){ return z > 0.f ? z : 0.f; }

// ---------------- Kernel A: precompute rank-1 GAT constants ----------------
// consts layout: [0]=c1 [1]=c2 [2..9]=P[8] [10..17]=Q[8] [18]=pA [19]=qA [20]=pB [21]=qB
__global__ void consts_kernel(const float* __restrict__ W1, const float* __restrict__ a1,
                              const float* __restrict__ W2, const float* __restrict__ a2,
                              float* __restrict__ consts){
  __shared__ float redA[256], redB[256];
  const int t = threadIdx.x;
  float s1 = 0.f, s2 = 0.f;
  for (int f = t; f < 512; f += 256){ float w = W1[f]; s1 += w*a1[f]; s2 += w*a1[512+f]; }
  redA[t] = s1; redB[t] = s2; __syncthreads();
  for (int st = 128; st > 0; st >>= 1){
    if (t < st){ redA[t] += redA[t+st]; redB[t] += redB[t+st]; }
    __syncthreads();
  }
  if (t == 0){ consts[0] = redA[0]; consts[1] = redB[0]; }
  __syncthreads();
  // P[g], Q[g]: 8 groups of 32 threads, each thread 16 f's
  const int g = t >> 5, seg = t & 31;
  float accP = 0.f, accQ = 0.f;
  for (int k = 0; k < 16; ++k){
    int f = seg*16 + k;
    float w = W1[f];
    float v = w * W2[f*8 + g];
    if (w > 0.f) accP += v; else accQ += v;
  }
  redA[t] = accP; redB[t] = accQ; __syncthreads();
  for (int st = 16; st > 0; st >>= 1){
    if (seg < st){ redA[t] += redA[t+st]; redB[t] += redB[t+st]; }
    __syncthreads();
  }
  if (seg == 0){ consts[2+g] = redA[t]; consts[10+g] = redB[t]; }
  __syncthreads();
  if (t == 0){
    float pA=0.f,qA=0.f,pB=0.f,qB=0.f;
    for (int gg = 0; gg < 8; ++gg){
      pA += consts[2+gg]*a2[gg];   qA += consts[10+gg]*a2[gg];
      pB += consts[2+gg]*a2[8+gg]; qB += consts[10+gg]*a2[8+gg];
    }
    consts[18]=pA; consts[19]=qA; consts[20]=pB; consts[21]=qB;
  }
}

// ---------------- Kernel B: fused GAT1 + GAT2 + attention pooling ----------
__global__ __launch_bounds__(256) void gat_kernel(
    const int*   __restrict__ adj, const float* __restrict__ feat,
    const float* __restrict__ timei,
    const float* __restrict__ Weight, const float* __restrict__ Wv,
    const float* __restrict__ consts, float* __restrict__ h_pool)
{
  const int b = blockIdx.x;
  const int t = threadIdx.x;
  const int lane = t & 127;   // column (pass1) or row (pass2) index
  const int half = t >> 7;    // which 64-element chunk of the other axis

  __shared__ float xs[128], tim[128], uu[128], colmax[128], colrcp[128], hm[128];
  __shared__ float partA[2][128], partB[2][128], partC[2][128], partD[2][128];
  __shared__ unsigned int maskW[512];   // maskW[j*4+w]: bits i=w*32..w*32+31 of column j
  __shared__ float V0s[128], V1s[128], A0s[128], A1s[128];

  const float c1 = consts[0], c2 = consts[1];
  const float pA = consts[18], qA = consts[19], pB = consts[20], qB = consts[21];

  if (t < 128){ xs[t] = feat[b*128 + t]; tim[t] = timei[b*128 + t]; }
  __syncthreads();

  const long adjBase = ((long)b) << 14;
  unsigned long long bits = 0ull;    // this thread's 64 mask bits (col=lane, rows half*64..)

  // ---- GAT1 column pass: max ----
  {
    float ecol = c2 * xs[lane];
    float mx = -INFINITY;
    int i0 = half*64;
    for (int k = 0; k < 64; ++k){
      int i = i0 + k;
      int a = adj[adjBase + (i<<7) + lane];
      float e;
      if (a > 0){ bits |= (1ull << k); e = lrelu(c1*xs[i] + ecol); }
      else e = NEGV;
      mx = fmaxf(mx, e);
    }
    partA[half][lane] = mx;
  }
  __syncthreads();
  if (t < 128) colmax[t] = fmaxf(partA[0][t], partA[1][t]);
  __syncthreads();
  // ---- GAT1 column pass: sum of exp; stash mask bits ----
  {
    float ecol = c2 * xs[lane];
    float cm = colmax[lane];
    float sum = 0.f;
    int i0 = half*64;
    for (int k = 0; k < 64; ++k){
      int i = i0 + k;
      float e = ((bits>>k)&1ull) ? lrelu(c1*xs[i] + ecol) : NEGV;
      sum += __expf(e - cm);
    }
    partA[half][lane] = sum;
    maskW[lane*4 + half*2 + 0] = (unsigned)(bits & 0xffffffffull);
    maskW[lane*4 + half*2 + 1] = (unsigned)(bits >> 32);
  }
  __syncthreads();
  if (t < 128) colrcp[t] = 1.f / (partA[0][t] + partA[1][t]);
  __syncthreads();
  // ---- GAT1 row pass: s_i = sum_j att_ij * x_j ----
  {
    const int i = lane;
    float erow = c1 * xs[i];
    const int wsh = i >> 5; const unsigned bsel = (unsigned)(i & 31);
    float s = 0.f;
    int j0 = half*64;
    for (int k = 0; k < 64; ++k){
      int j = j0 + k;
      unsigned mw = maskW[j*4 + wsh];
      float e = ((mw>>bsel)&1u) ? lrelu(erow + c2*xs[j]) : NEGV;
      s += __expf(e - colmax[j]) * colrcp[j] * xs[j];
    }
    partB[half][lane] = s;
  }
  __syncthreads();
  if (t < 128) uu[t] = partB[0][t] + partB[1][t];
  __syncthreads();

  // ---- GAT2 column pass: max ----
  {
    float uj = uu[lane];
    float ecol = (uj >= 0.f ? pB : qB) * uj;
    float mx = -INFINITY;
    int i0 = half*64;
    for (int k = 0; k < 64; ++k){
      int i = i0 + k;
      float ui = uu[i];
      float erow = (ui >= 0.f ? pA : qA) * ui;
      float e = ((bits>>k)&1ull) ? lrelu(erow + ecol) : NEGV;
      mx = fmaxf(mx, e);
    }
    partA[half][lane] = mx;
  }
  __syncthreads();
  if (t < 128) colmax[t] = fmaxf(partA[0][t], partA[1][t]);
  __syncthreads();
  // ---- GAT2 column pass: sum ----
  {
    float uj = uu[lane];
    float ecol = (uj >= 0.f ? pB : qB) * uj;
    float cm = colmax[lane];
    float sum = 0.f;
    int i0 = half*64;
    for (int k = 0; k < 64; ++k){
      int i = i0 + k;
      float ui = uu[i];
      float erow = (ui >= 0.f ? pA : qA) * ui;
      float e = ((bits>>k)&1ull) ? lrelu(erow + ecol) : NEGV;
      sum += __expf(e - cm);
    }
    partA[half][lane] = sum;
  }
  __syncthreads();
  if (t < 128) colrcp[t] = 1.f / (partA[0][t] + partA[1][t]);
  __syncthreads();
  // ---- GAT2 row pass: sp, sn ----
  {
    const int i = lane;
    float ui = uu[i];
    float erow = (ui >= 0.f ? pA : qA) * ui;
    const int wsh = i >> 5; const unsigned bsel = (unsigned)(i & 31);
    float sp = 0.f, sn = 0.f;
    int j0 = half*64;
    for (int k = 0; k < 64; ++k){
      int j = j0 + k;
      float uj = uu[j];
      float ecol = (uj >= 0.f ? pB : qB) * uj;
      unsigned mw = maskW[j*4 + wsh];
      float e = ((mw>>bsel)&1u) ? lrelu(erow + ecol) : NEGV;
      float att = __expf(e - colmax[j]) * colrcp[j];
      if (uj >= 0.f) sp += att*uj; else sn += att*uj;
    }
    partA[half][lane] = sp; partB[half][lane] = sn;
  }
  __syncthreads();
  if (t < 128){
    float sp = partA[0][t] + partA[1][t];
    float sn = partB[0][t] + partB[1][t];
    float acc = 0.f;
    for (int g = 0; g < 8; ++g){
      float v = sp*consts[2+g] + sn*consts[10+g];
      acc += reluf(v);
    }
    hm[t] = 0.125f * acc;
  }
  __syncthreads();

  // ---- attention pooling: A0,A1 (Weight), V0,V1 (Wv) ----
  {
    const int n = lane;
    float a0=0.f, a1v=0.f, v0=0.f, v1=0.f;
    int m0 = half*64;
    for (int k = 0; k < 64; ++k){
      int m = m0 + k;
      float hmv = hm[m], tv = tim[m];
      float wgt = Weight[(m<<7) + n];
      float wvv = Wv[(m<<7) + n];
      a0 += hmv*wgt; a1v += tv*wgt; v0 += hmv*wvv; v1 += tv*wvv;
    }
    partA[half][lane]=a0; partB[half][lane]=a1v; partC[half][lane]=v0; partD[half][lane]=v1;
  }
  __syncthreads();
  if (t < 128){
    A0s[t] = partA[0][t]+partA[1][t];
    A1s[t] = partB[0][t]+partB[1][t];
    V0s[t] = partC[0][t]+partC[1][t];
    V1s[t] = partD[0][t]+partD[1][t];
  }
  __syncthreads();
  if (t < 128){
    const int n = t;
    float a0 = A0s[n], a1v = A1s[n];
    float mx = fmaxf(a0, a1v);
    float e0 = __expf(a0 - mx), e1 = __expf(a1v - mx);
    float rs = 1.f/(e0 + e1);
    float att0 = e0*rs, att1 = e1*rs;
    float r0, r1;
    if (n < 64){ r0 = V0s[2*n]; r1 = V0s[2*n+1]; }
    else       { r0 = V1s[2*n-128]; r1 = V1s[2*n-127]; }
    h_pool[b*128 + n] = reluf(r0)*att0 + reluf(r1)*att1;
  }
}

// ---------------- Kernel C: 2-layer scalar LSTM ----------------
__global__ void lstm_kernel(const float* __restrict__ ipop,
  const float* __restrict__ wih0, const float* __restrict__ whh0,
  const float* __restrict__ bih0, const float* __restrict__ bhh0,
  const float* __restrict__ wih1, const float* __restrict__ whh1,
  const float* __restrict__ bih1, const float* __restrict__ bhh1,
  float* __restrict__ ip_out)
{
  int b = blockIdx.x*blockDim.x + threadIdx.x;
  if (b >= 512) return;
  float wi0[4], wh0[4], bb0[4], wi1[4], wh1[4], bb1[4];
  for (int k = 0; k < 4; ++k){
    wi0[k]=wih0[k]; wh0[k]=whh0[k]; bb0[k]=bih0[k]+bhh0[k];
    wi1[k]=wih1[k]; wh1[k]=whh1[k]; bb1[k]=bih1[k]+bhh1[k];
  }
  float h1=0.f, c1v=0.f, h2=0.f, c2v=0.f;
  for (int tt = 0; tt < 64; ++tt){
    float x = ipop[b*64 + tt];
    float gi = sigm (x*wi0[0] + h1*wh0[0] + bb0[0]);
    float gf = sigm (x*wi0[1] + h1*wh0[1] + bb0[1]);
    float gg = tanhf(x*wi0[2] + h1*wh0[2] + bb0[2]);
    float go = sigm (x*wi0[3] + h1*wh0[3] + bb0[3]);
    c1v = gf*c1v + gi*gg; h1 = go*tanhf(c1v);
    float hi2 = sigm (h1*wi1[0] + h2*wh1[0] + bb1[0]);
    float hf2 = sigm (h1*wi1[1] + h2*wh1[1] + bb1[1]);
    float hg2 = tanhf(h1*wi1[2] + h2*wh1[2] + bb1[2]);
    float ho2 = sigm (h1*wi1[3] + h2*wh1[3] + bb1[3]);
    c2v = hf2*c2v + hi2*hg2; h2 = ho2*tanhf(c2v);
    ip_out[b*64 + tt] = h2;
  }
}

// ---------------- Kernel D: MHA + residual + MLP head ----------------
__global__ __launch_bounds__(192) void head_kernel(
  const float* __restrict__ h_pool, const float* __restrict__ ip,
  const float* __restrict__ mha_in_w, const float* __restrict__ mha_in_b,
  const float* __restrict__ mha_out_w, const float* __restrict__ mha_out_b,
  const float* __restrict__ fl1_w, const float* __restrict__ fl1_b,
  const float* __restrict__ fl2_w, const float* __restrict__ fl2_b,
  const float* __restrict__ fl3_w, const float* __restrict__ fl3_b,
  float* __restrict__ out)
{
  const int b = blockIdx.x, t = threadIdx.x;
  __shared__ float hq[192], h2s[192], o1[128], o2s[32];
  if (t < 128) hq[t] = h_pool[b*128 + t];
  else         hq[t] = ip[b*64 + (t - 128)];
  __syncthreads();
  const float wq = mha_in_w[0], wk = mha_in_w[1], wv = mha_in_w[2];
  const float bq = mha_in_b[0], bk = mha_in_b[1], bv = mha_in_b[2];
  const float wo = mha_out_w[0], bo = mha_out_b[0];
  float qi = hq[t]*wq + bq;
  float mx = -INFINITY;
  for (int j = 0; j < 192; ++j) mx = fmaxf(mx, qi*(hq[j]*wk + bk));
  float den = 0.f, num = 0.f;
  for (int j = 0; j < 192; ++j){
    float e = __expf(qi*(hq[j]*wk + bk) - mx);
    den += e; num += e*(hq[j]*wv + bv);
  }
  h2s[t] = (num/den)*wo + bo + hq[t];
  __syncthreads();
  if (t < 128){
    float acc = fl1_b[t];
    for (int i = 0; i < 192; ++i) acc += h2s[i]*fl1_w[i*128 + t];
    o1[t] = reluf(acc);
  }
  __syncthreads();
  if (t < 32){
    float acc = fl2_b[t];
    for (int i = 0; i < 128; ++i) acc += o1[i]*fl2_w[i*32 + t];
    o2s[t] = tanhf(acc);
  }
  __syncthreads();
  if (t == 0){
    float acc = fl3_b[0];
    for (int p = 0; p < 32; ++p) acc += o2s[p]*fl3_w[p];
    out[b] = reluf(acc);
  }
}

extern "C" void kernel_launch(void* const* d_in, const int* in_sizes, int n_in,
                              void* d_out, int out_size, void* d_ws, size_t ws_size,
                              hipStream_t stream) {
  const int*   adj    = (const int*)  d_in[0];
  const float* feat   = (const float*)d_in[1];
  const float* timei  = (const float*)d_in[2];
  const float* ipop   = (const float*)d_in[3];
  const float* W1     = (const float*)d_in[4];
  const float* a1     = (const float*)d_in[5];
  const float* W2     = (const float*)d_in[6];
  const float* a2     = (const float*)d_in[7];
  const float* Weight = (const float*)d_in[8];
  const float* Wv     = (const float*)d_in[9];
  const float* wih0   = (const float*)d_in[10];
  const float* whh0   = (const float*)d_in[11];
  const float* bih0   = (const float*)d_in[12];
  const float* bhh0   = (const float*)d_in[13];
  const float* wih1   = (const float*)d_in[14];
  const float* whh1   = (const float*)d_in[15];
  const float* bih1   = (const float*)d_in[16];
  const float* bhh1   = (const float*)d_in[17];
  const float* mha_in_w  = (const float*)d_in[18];
  const float* mha_in_b  = (const float*)d_in[19];
  const float* mha_out_w = (const float*)d_in[20];
  const float* mha_out_b = (const float*)d_in[21];
  const float* fl1_w = (const float*)d_in[22];
  const float* fl1_b = (const float*)d_in[23];
  const float* fl2_w = (const float*)d_in[24];
  const float* fl2_b = (const float*)d_in[25];
  const float* fl3_w = (const float*)d_in[26];
  const float* fl3_b = (const float*)d_in[27];

  float* ws      = (float*)d_ws;
  float* consts  = ws;                  // 32 floats
  float* h_pool  = ws + 32;             // 512*128
  float* ip      = ws + 32 + 512*128;   // 512*64

  consts_kernel<<<1, 256, 0, stream>>>(W1, a1, W2, a2, consts);
  lstm_kernel<<<2, 256, 0, stream>>>(ipop, wih0, whh0, bih0, bhh0,
                                     wih1, whh1, bih1, bhh1, ip);
  gat_kernel<<<512, 256, 0, stream>>>(adj, feat, timei, Weight, Wv, consts, h_pool);
  head_kernel<<<512, 192, 0, stream>>>(h_pool, ip,
                                       mha_in_w, mha_in_b, mha_out_w, mha_out_b,
                                       fl1_w, fl1_b, fl2_w, fl2_b, fl3_w, fl3_b,
                                       (float*)d_out);
}

// Round 2
// 84.964 us; speedup vs baseline: 1.5013x; 1.5013x over previous
//
#include <hip/hip_runtime.h>
#include <math.h>

__device__ __forceinline__ float lrelu(float z){ return z > 0.f ? z : 0.5f*z; }
__device__ __forceinline__ float reluf(float z){ return z > 0.f ? z : 0.f; }
__device__ __forceinline__ float sigm(float z){ return 1.f/(1.f + __expf(-z)); }
__device__ __forceinline__ float tanh_fast(float z){ return 2.f/(1.f + __expf(-2.f*z)) - 1.f; }

// ---------------- Kernel A: precompute rank-1 GAT constants ----------------
// consts layout: [0]=c1 [1]=c2 [2..9]=P[8] [10..17]=Q[8] [18]=pA [19]=qA [20]=pB [21]=qB
__global__ void consts_kernel(const float* __restrict__ W1, const float* __restrict__ a1,
                              const float* __restrict__ W2, const float* __restrict__ a2,
                              float* __restrict__ consts){
  __shared__ float redA[256], redB[256];
  const int t = threadIdx.x;
  float s1 = 0.f, s2 = 0.f;
  for (int f = t; f < 512; f += 256){ float w = W1[f]; s1 += w*a1[f]; s2 += w*a1[512+f]; }
  redA[t] = s1; redB[t] = s2; __syncthreads();
  for (int st = 128; st > 0; st >>= 1){
    if (t < st){ redA[t] += redA[t+st]; redB[t] += redB[t+st]; }
    __syncthreads();
  }
  if (t == 0){ consts[0] = redA[0]; consts[1] = redB[0]; }
  __syncthreads();
  const int g = t >> 5, seg = t & 31;
  float accP = 0.f, accQ = 0.f;
  for (int k = 0; k < 16; ++k){
    int f = seg*16 + k;
    float w = W1[f];
    float v = w * W2[f*8 + g];
    if (w > 0.f) accP += v; else accQ += v;
  }
  redA[t] = accP; redB[t] = accQ; __syncthreads();
  for (int st = 16; st > 0; st >>= 1){
    if (seg < st){ redA[t] += redA[t+st]; redB[t] += redB[t+st]; }
    __syncthreads();
  }
  if (seg == 0){ consts[2+g] = redA[t]; consts[10+g] = redB[t]; }
  __syncthreads();
  if (t == 0){
    float pA=0.f,qA=0.f,pB=0.f,qB=0.f;
    for (int gg = 0; gg < 8; ++gg){
      pA += consts[2+gg]*a2[gg];   qA += consts[10+gg]*a2[gg];
      pB += consts[2+gg]*a2[8+gg]; qB += consts[10+gg]*a2[8+gg];
    }
    consts[18]=pA; consts[19]=qA; consts[20]=pB; consts[21]=qB;
  }
}

// ---------------- Fused: GAT1 + GAT2 + pooling (blocks 0..511), LSTM (512..519) -----
__global__ __launch_bounds__(1024) void fused_kernel(
    const int*   __restrict__ adj, const float* __restrict__ feat,
    const float* __restrict__ timei,
    const float* __restrict__ Weight, const float* __restrict__ Wv,
    const float* __restrict__ consts, float* __restrict__ h_pool,
    const float* __restrict__ ipop,
    const float* __restrict__ wih0, const float* __restrict__ whh0,
    const float* __restrict__ bih0, const float* __restrict__ bhh0,
    const float* __restrict__ wih1, const float* __restrict__ whh1,
    const float* __restrict__ bih1, const float* __restrict__ bhh1,
    float* __restrict__ ip_out)
{
  if (blockIdx.x >= 512){
    // ----- LSTM part: 8 blocks x 64 threads = 512 sequences -----
    const int t = threadIdx.x;
    if (t >= 64) return;
    const int b = (blockIdx.x - 512)*64 + t;
    float wi0[4], wh0[4], bb0[4], wi1[4], wh1[4], bb1[4];
    for (int k = 0; k < 4; ++k){
      wi0[k]=wih0[k]; wh0[k]=whh0[k]; bb0[k]=bih0[k]+bhh0[k];
      wi1[k]=wih1[k]; wh1[k]=whh1[k]; bb1[k]=bih1[k]+bhh1[k];
    }
    float h1=0.f, c1v=0.f, h2=0.f, c2v=0.f;
    for (int tt = 0; tt < 64; ++tt){
      float x = ipop[b*64 + tt];
      float gi = sigm    (__fmaf_rn(x, wi0[0], __fmaf_rn(h1, wh0[0], bb0[0])));
      float gf = sigm    (__fmaf_rn(x, wi0[1], __fmaf_rn(h1, wh0[1], bb0[1])));
      float gg = tanh_fast(__fmaf_rn(x, wi0[2], __fmaf_rn(h1, wh0[2], bb0[2])));
      float go = sigm    (__fmaf_rn(x, wi0[3], __fmaf_rn(h1, wh0[3], bb0[3])));
      c1v = gf*c1v + gi*gg; h1 = go*tanh_fast(c1v);
      float hi2 = sigm    (__fmaf_rn(h1, wi1[0], __fmaf_rn(h2, wh1[0], bb1[0])));
      float hf2 = sigm    (__fmaf_rn(h1, wi1[1], __fmaf_rn(h2, wh1[1], bb1[1])));
      float hg2 = tanh_fast(__fmaf_rn(h1, wi1[2], __fmaf_rn(h2, wh1[2], bb1[2])));
      float ho2 = sigm    (__fmaf_rn(h1, wi1[3], __fmaf_rn(h2, wh1[3], bb1[3])));
      c2v = hf2*c2v + hi2*hg2; h2 = ho2*tanh_fast(c2v);
      ip_out[b*64 + tt] = h2;
    }
    return;
  }

  // ----- GAT part: one batch per block, 1024 threads -----
  const int b = blockIdx.x;
  const int t = threadIdx.x;
  const int lane = t & 127;   // column j (col passes) / row i (row passes)
  const int grp  = t >> 7;    // 0..7: 16-element chunk of the other axis

  __shared__ float xs[128], tim[128], uu[128], eAs[128], eBs[128];
  __shared__ float colsub[128], colrcp[128], hm[128];
  __shared__ float red[4][8][128];
  __shared__ unsigned short maskS[128][8];  // maskS[j][g]: rows g*16..g*16+15 of column j
  __shared__ float sxmax, sxmin, sEAmax;

  const float c1 = consts[0], c2 = consts[1];
  const float pA = consts[18], qA = consts[19], pB = consts[20], qB = consts[21];

  if (t < 128){ xs[t] = feat[b*128 + t]; tim[t] = timei[b*128 + t]; }
  __syncthreads();
  if (t < 64){
    float mx = fmaxf(xs[t], xs[t+64]);
    float mn = fminf(xs[t], xs[t+64]);
    for (int off = 32; off; off >>= 1){
      mx = fmaxf(mx, __shfl_xor(mx, off));
      mn = fminf(mn, __shfl_xor(mn, off));
    }
    if (t == 0){ sxmax = mx; sxmin = mn; }
  }
  __syncthreads();

  const float maxE1 = (c1 >= 0.f) ? c1*sxmax : c1*sxmin;  // max_i c1*x_i
  const long adjBase = ((long)b) << 14;
  unsigned int bits = 0;   // 16 mask bits: rows grp*16..grp*16+15, column=lane

  // ---- GAT1 column pass: masked sum of exp(e - cb_j), build bitmask ----
  {
    const int j = lane;
    const float ecol = c2 * xs[j];
    const float cb = lrelu(maxE1 + ecol);     // exact softmax shift (lrelu monotone)
    float sum = 0.f;
    const int i0 = grp*16;
    for (int k = 0; k < 16; ++k){
      int i = i0 + k;
      int a = adj[adjBase + (i<<7) + j];
      float e = lrelu(__fmaf_rn(c1, xs[i], ecol));
      float v = __expf(e - cb);
      if (a > 0){ bits |= (1u << k); sum += v; }
    }
    red[0][grp][j] = sum;
    maskS[j][grp] = (unsigned short)bits;
    if (grp == 0) colsub[j] = cb;
  }
  __syncthreads();
  if (t < 128){
    float s = 0.f;
    for (int g = 0; g < 8; ++g) s += red[0][g][t];
    colrcp[t] = 1.f / s;
  }
  __syncthreads();
  // ---- GAT1 row pass: u_i = sum_j att_ij x_j ----
  {
    const int i = lane;
    const float erow = c1 * xs[i];
    const int w = i >> 4; const int bsel = i & 15;
    float s = 0.f;
    const int j0 = grp*16;
    for (int k = 0; k < 16; ++k){
      int j = j0 + k;
      float xj = xs[j];
      float e = lrelu(__fmaf_rn(c2, xj, erow));
      float att = __expf(e - colsub[j]) * colrcp[j];
      float m = (float)((maskS[j][w] >> bsel) & 1);
      s = __fmaf_rn(m*att, xj, s);
    }
    red[1][grp][i] = s;
  }
  __syncthreads();
  if (t < 128){
    float u = 0.f;
    for (int g = 0; g < 8; ++g) u += red[1][g][t];
    uu[t] = u;
    eAs[t] = (u >= 0.f ? pA : qA) * u;
    eBs[t] = (u >= 0.f ? pB : qB) * u;
  }
  __syncthreads();
  if (t < 64){
    float mx = fmaxf(eAs[t], eAs[t+64]);
    for (int off = 32; off; off >>= 1) mx = fmaxf(mx, __shfl_xor(mx, off));
    if (t == 0) sEAmax = mx;
  }
  __syncthreads();

  // ---- GAT2 column pass ----
  {
    const int j = lane;
    const float ecol = eBs[j];
    const float cb = lrelu(sEAmax + ecol);
    float sum = 0.f;
    const int i0 = grp*16;
    for (int k = 0; k < 16; ++k){
      int i = i0 + k;
      float e = lrelu(eAs[i] + ecol);
      float v = __expf(e - cb);
      sum += ((bits >> k) & 1u) ? v : 0.f;
    }
    red[0][grp][j] = sum;
    if (grp == 0) colsub[j] = cb;
  }
  __syncthreads();
  if (t < 128){
    float s = 0.f;
    for (int g = 0; g < 8; ++g) s += red[0][g][t];
    colrcp[t] = 1.f / s;
  }
  __syncthreads();
  // ---- GAT2 row pass: sp, sn ----
  {
    const int i = lane;
    const float erow = eAs[i];
    const int w = i >> 4; const int bsel = i & 15;
    float sp = 0.f, sn = 0.f;
    const int j0 = grp*16;
    for (int k = 0; k < 16; ++k){
      int j = j0 + k;
      float uj = uu[j];
      float e = lrelu(erow + eBs[j]);
      float att = __expf(e - colsub[j]) * colrcp[j];
      att *= (float)((maskS[j][w] >> bsel) & 1);
      sp = __fmaf_rn(att, fmaxf(uj, 0.f), sp);
      sn = __fmaf_rn(att, fminf(uj, 0.f), sn);
    }
    red[0][grp][i] = sp; red[1][grp][i] = sn;
  }
  __syncthreads();
  if (t < 128){
    float sp = 0.f, sn = 0.f;
    for (int g = 0; g < 8; ++g){ sp += red[0][g][t]; sn += red[1][g][t]; }
    float acc = 0.f;
    for (int g2 = 0; g2 < 8; ++g2) acc += reluf(__fmaf_rn(sp, consts[2+g2], sn*consts[10+g2]));
    hm[t] = 0.125f * acc;
  }
  __syncthreads();

  // ---- attention pooling ----
  {
    const int n = lane;
    float a0=0.f, a1v=0.f, v0=0.f, v1=0.f;
    const int m0 = grp*16;
    for (int k = 0; k < 16; ++k){
      int m = m0 + k;
      float hmv = hm[m], tv = tim[m];
      float wgt = Weight[(m<<7) + n];
      float wvv = Wv[(m<<7) + n];
      a0 = __fmaf_rn(hmv, wgt, a0); a1v = __fmaf_rn(tv, wgt, a1v);
      v0 = __fmaf_rn(hmv, wvv, v0); v1 = __fmaf_rn(tv, wvv, v1);
    }
    red[0][grp][n]=a0; red[1][grp][n]=a1v; red[2][grp][n]=v0; red[3][grp][n]=v1;
  }
  __syncthreads();
  if (t < 128){
    float A0=0.f,A1=0.f,V0=0.f,V1=0.f;
    for (int g = 0; g < 8; ++g){
      A0+=red[0][g][t]; A1+=red[1][g][t]; V0+=red[2][g][t]; V1+=red[3][g][t];
    }
    colsub[t] = A0; colrcp[t] = A1; eAs[t] = V0; eBs[t] = V1;
  }
  __syncthreads();
  if (t < 128){
    float a0 = colsub[t], a1v = colrcp[t];
    float mx = fmaxf(a0, a1v);
    float e0 = __expf(a0 - mx), e1 = __expf(a1v - mx);
    float rs = 1.f/(e0 + e1);
    float r0, r1;
    if (t < 64){ r0 = eAs[2*t]; r1 = eAs[2*t+1]; }
    else       { r0 = eBs[2*t-128]; r1 = eBs[2*t-127]; }
    h_pool[b*128 + t] = (reluf(r0)*e0 + reluf(r1)*e1)*rs;
  }
}

// ---------------- Kernel D: MHA + residual + MLP head ----------------
__global__ __launch_bounds__(192) void head_kernel(
  const float* __restrict__ h_pool, const float* __restrict__ ip,
  const float* __restrict__ mha_in_w, const float* __restrict__ mha_in_b,
  const float* __restrict__ mha_out_w, const float* __restrict__ mha_out_b,
  const float* __restrict__ fl1_w, const float* __restrict__ fl1_b,
  const float* __restrict__ fl2_w, const float* __restrict__ fl2_b,
  const float* __restrict__ fl3_w, const float* __restrict__ fl3_b,
  float* __restrict__ out)
{
  const int b = blockIdx.x, t = threadIdx.x;
  __shared__ float hq[192], ks[192], vs[192], h2s[192], o1[128], o2s[32];
  const float wq = mha_in_w[0], wk = mha_in_w[1], wv = mha_in_w[2];
  const float bq = mha_in_b[0], bk = mha_in_b[1], bv = mha_in_b[2];
  const float wo = mha_out_w[0], bo = mha_out_b[0];
  float hv = (t < 128) ? h_pool[b*128 + t] : ip[b*64 + (t - 128)];
  hq[t] = hv;
  ks[t] = __fmaf_rn(hv, wk, bk);
  vs[t] = __fmaf_rn(hv, wv, bv);
  __syncthreads();
  float qi = __fmaf_rn(hv, wq, bq);
  float mx = -INFINITY;
  for (int j = 0; j < 192; ++j) mx = fmaxf(mx, qi*ks[j]);
  float den = 0.f, num = 0.f;
  for (int j = 0; j < 192; ++j){
    float e = __expf(__fmaf_rn(qi, ks[j], -mx));
    den += e; num = __fmaf_rn(e, vs[j], num);
  }
  h2s[t] = __fmaf_rn(num/den, wo, bo) + hv;
  __syncthreads();
  if (t < 128){
    float acc = fl1_b[t];
    for (int i = 0; i < 192; ++i) acc = __fmaf_rn(h2s[i], fl1_w[i*128 + t], acc);
    o1[t] = reluf(acc);
  }
  __syncthreads();
  if (t < 32){
    float acc = fl2_b[t];
    for (int i = 0; i < 128; ++i) acc = __fmaf_rn(o1[i], fl2_w[i*32 + t], acc);
    o2s[t] = tanh_fast(acc);
  }
  __syncthreads();
  if (t == 0){
    float acc = fl3_b[0];
    for (int p = 0; p < 32; ++p) acc = __fmaf_rn(o2s[p], fl3_w[p], acc);
    out[b] = reluf(acc);
  }
}

extern "C" void kernel_launch(void* const* d_in, const int* in_sizes, int n_in,
                              void* d_out, int out_size, void* d_ws, size_t ws_size,
                              hipStream_t stream) {
  const int*   adj    = (const int*)  d_in[0];
  const float* feat   = (const float*)d_in[1];
  const float* timei  = (const float*)d_in[2];
  const float* ipop   = (const float*)d_in[3];
  const float* W1     = (const float*)d_in[4];
  const float* a1     = (const float*)d_in[5];
  const float* W2     = (const float*)d_in[6];
  const float* a2     = (const float*)d_in[7];
  const float* Weight = (const float*)d_in[8];
  const float* Wv     = (const float*)d_in[9];
  const float* wih0   = (const float*)d_in[10];
  const float* whh0   = (const float*)d_in[11];
  const float* bih0   = (const float*)d_in[12];
  const float* bhh0   = (const float*)d_in[13];
  const float* wih1   = (const float*)d_in[14];
  const float* whh1   = (const float*)d_in[15];
  const float* bih1   = (const float*)d_in[16];
  const float* bhh1   = (const float*)d_in[17];
  const float* mha_in_w  = (const float*)d_in[18];
  const float* mha_in_b  = (const float*)d_in[19];
  const float* mha_out_w = (const float*)d_in[20];
  const float* mha_out_b = (const float*)d_in[21];
  const float* fl1_w = (const float*)d_in[22];
  const float* fl1_b = (const float*)d_in[23];
  const float* fl2_w = (const float*)d_in[24];
  const float* fl2_b = (const float*)d_in[25];
  const float* fl3_w = (const float*)d_in[26];
  const float* fl3_b = (const float*)d_in[27];

  float* ws      = (float*)d_ws;
  float* consts  = ws;                  // 32 floats
  float* h_pool  = ws + 32;             // 512*128
  float* ip      = ws + 32 + 512*128;   // 512*64

  consts_kernel<<<1, 256, 0, stream>>>(W1, a1, W2, a2, consts);
  fused_kernel<<<520, 1024, 0, stream>>>(adj, feat, timei, Weight, Wv, consts, h_pool,
                                         ipop, wih0, whh0, bih0, bhh0,
                                         wih1, whh1, bih1, bhh1, ip);
  head_kernel<<<512, 192, 0, stream>>>(h_pool, ip,
                                       mha_in_w, mha_in_b, mha_out_w, mha_out_b,
                                       fl1_w, fl1_b, fl2_w, fl2_b, fl3_w, fl3_b,
                                       (float*)d_out);
}

// Round 3
// 74.309 us; speedup vs baseline: 1.7166x; 1.1434x over previous
//
#include <hip/hip_runtime.h>
#include <math.h>

typedef unsigned int uint;
typedef unsigned long long ull;

__device__ __forceinline__ float lrelu(float z){ return z > 0.f ? z : 0.5f*z; }
__device__ __forceinline__ float reluf(float z){ return fmaxf(z, 0.f); }
__device__ __forceinline__ float sigm(float z){ return 1.f/(1.f + __expf(-z)); }
__device__ __forceinline__ float tanh_fast(float z){ return 2.f/(1.f + __expf(-2.f*z)) - 1.f; }

// ============ K1: adjacency bit-pack (blocks 0..1023) + LSTM (1024..1031) + consts (1032) ============
// packed[W], W = b*512 + i*4 + w : bit k = (adj[b][i][w*32+k] > 0)
// consts layout: [0]=c1 [1]=c2 [2..9]=P[8] [10..17]=Q[8] [18]=pA [19]=qA [20]=pB [21]=qB
__global__ __launch_bounds__(256) void prep_kernel(
    const int* __restrict__ adj, uint* __restrict__ packed,
    const float* __restrict__ W1, const float* __restrict__ a1,
    const float* __restrict__ W2, const float* __restrict__ a2,
    float* __restrict__ consts,
    const float* __restrict__ ipop,
    const float* __restrict__ wih0, const float* __restrict__ whh0,
    const float* __restrict__ bih0, const float* __restrict__ bhh0,
    const float* __restrict__ wih1, const float* __restrict__ whh1,
    const float* __restrict__ bih1, const float* __restrict__ bhh1,
    float* __restrict__ ip_out)
{
  __shared__ float redA[256], redB[256];
  const int bid = blockIdx.x;
  const int t = threadIdx.x;

  if (bid < 1024){
    // ---- bit-pack: one 32-bit word per thread, 8 independent int4 loads ----
    const int W = bid*256 + t;
    const long base = (long)W * 32;
    const int4* p = (const int4*)(adj + base);
    int4 v0 = p[0], v1 = p[1], v2 = p[2], v3 = p[3];
    int4 v4 = p[4], v5 = p[5], v6 = p[6], v7 = p[7];
    uint w = 0;
    #define PACK4(v, s) \
      w |= (uint)((v).x & 1) << ((s)+0); w |= (uint)((v).y & 1) << ((s)+1); \
      w |= (uint)((v).z & 1) << ((s)+2); w |= (uint)((v).w & 1) << ((s)+3);
    PACK4(v0, 0) PACK4(v1, 4) PACK4(v2, 8) PACK4(v3, 12)
    PACK4(v4,16) PACK4(v5,20) PACK4(v6,24) PACK4(v7,28)
    #undef PACK4
    packed[W] = w;
    return;
  }
  if (bid < 1032){
    // ---- LSTM: 8 blocks x 64 threads = 512 sequences ----
    if (t >= 64) return;
    const int b = (bid - 1024)*64 + t;
    float wi0[4], wh0[4], bb0[4], wi1[4], wh1[4], bb1[4];
    #pragma unroll
    for (int k = 0; k < 4; ++k){
      wi0[k]=wih0[k]; wh0[k]=whh0[k]; bb0[k]=bih0[k]+bhh0[k];
      wi1[k]=wih1[k]; wh1[k]=whh1[k]; bb1[k]=bih1[k]+bhh1[k];
    }
    float h1=0.f, c1v=0.f, h2=0.f, c2v=0.f;
    for (int tt = 0; tt < 64; ++tt){
      float x = ipop[b*64 + tt];
      float gi = sigm     (__fmaf_rn(x, wi0[0], __fmaf_rn(h1, wh0[0], bb0[0])));
      float gf = sigm     (__fmaf_rn(x, wi0[1], __fmaf_rn(h1, wh0[1], bb0[1])));
      float gg = tanh_fast(__fmaf_rn(x, wi0[2], __fmaf_rn(h1, wh0[2], bb0[2])));
      float go = sigm     (__fmaf_rn(x, wi0[3], __fmaf_rn(h1, wh0[3], bb0[3])));
      c1v = gf*c1v + gi*gg; h1 = go*tanh_fast(c1v);
      float hi2 = sigm     (__fmaf_rn(h1, wi1[0], __fmaf_rn(h2, wh1[0], bb1[0])));
      float hf2 = sigm     (__fmaf_rn(h1, wi1[1], __fmaf_rn(h2, wh1[1], bb1[1])));
      float hg2 = tanh_fast(__fmaf_rn(h1, wi1[2], __fmaf_rn(h2, wh1[2], bb1[2])));
      float ho2 = sigm     (__fmaf_rn(h1, wi1[3], __fmaf_rn(h2, wh1[3], bb1[3])));
      c2v = hf2*c2v + hi2*hg2; h2 = ho2*tanh_fast(c2v);
      ip_out[b*64 + tt] = h2;
    }
    return;
  }
  // ---- consts block ----
  {
    float s1 = 0.f, s2 = 0.f;
    for (int f = t; f < 512; f += 256){ float w = W1[f]; s1 += w*a1[f]; s2 += w*a1[512+f]; }
    redA[t] = s1; redB[t] = s2; __syncthreads();
    for (int st = 128; st > 0; st >>= 1){
      if (t < st){ redA[t] += redA[t+st]; redB[t] += redB[t+st]; }
      __syncthreads();
    }
    if (t == 0){ consts[0] = redA[0]; consts[1] = redB[0]; }
    __syncthreads();
    const int g = t >> 5, seg = t & 31;
    float accP = 0.f, accQ = 0.f;
    for (int k = 0; k < 16; ++k){
      int f = seg*16 + k;
      float w = W1[f];
      float v = w * W2[f*8 + g];
      if (w > 0.f) accP += v; else accQ += v;
    }
    redA[t] = accP; redB[t] = accQ; __syncthreads();
    for (int st = 16; st > 0; st >>= 1){
      if (seg < st){ redA[t] += redA[t+st]; redB[t] += redB[t+st]; }
      __syncthreads();
    }
    if (seg == 0){ consts[2+g] = redA[t]; consts[10+g] = redB[t]; }
    __syncthreads();
    if (t == 0){
      float pA=0.f,qA=0.f,pB=0.f,qB=0.f;
      for (int gg = 0; gg < 8; ++gg){
        pA += consts[2+gg]*a2[gg];   qA += consts[10+gg]*a2[gg];
        pB += consts[2+gg]*a2[8+gg]; qB += consts[10+gg]*a2[8+gg];
      }
      consts[18]=pA; consts[19]=qA; consts[20]=pB; consts[21]=qB;
    }
  }
}

// ============ K2: GAT1 + GAT2 + pooling + MHA + MLP head, one batch per 256-thread block ============
__global__ __launch_bounds__(256) void gat_head_kernel(
    const uint* __restrict__ packed, const float* __restrict__ feat,
    const float* __restrict__ timei,
    const float* __restrict__ Weight, const float* __restrict__ Wv,
    const float* __restrict__ consts, const float* __restrict__ ip,
    const float* __restrict__ mha_in_w, const float* __restrict__ mha_in_b,
    const float* __restrict__ mha_out_w, const float* __restrict__ mha_out_b,
    const float* __restrict__ fl1_w, const float* __restrict__ fl1_b,
    const float* __restrict__ fl2_w, const float* __restrict__ fl2_b,
    const float* __restrict__ fl3_w, const float* __restrict__ fl3_b,
    float* __restrict__ out)
{
  const int b = blockIdx.x, t = threadIdx.x;
  const int lane = t & 127, h = t >> 7;      // h in {0,1}

  __shared__ float xs[128], tim[128], uu[128], eA[128], eB[128], cs[128], cr[128], hm[128];
  __shared__ uint mk[128][4];                // row-major mask bits
  __shared__ float red2[2][128];
  __shared__ float pool4[4][2][128];
  __shared__ float kv[192][2];
  __shared__ float hq[192], h2s[192], o2s[32];
  __shared__ float sred[8];

  const float c1 = consts[0], c2 = consts[1];
  const float pA = consts[18], qA = consts[19], pB = consts[20], qB = consts[21];

  if (t < 128){
    xs[t]  = feat[b*128 + t];
    tim[t] = timei[b*128 + t];
    ((uint4*)mk)[t] = ((const uint4*)(packed + (long)b*512))[t];
  }
  __syncthreads();
  if (t < 64){
    float mx = fmaxf(xs[t], xs[t+64]);
    float mn = fminf(xs[t], xs[t+64]);
    #pragma unroll
    for (int off = 32; off; off >>= 1){
      mx = fmaxf(mx, __shfl_xor(mx, off));
      mn = fminf(mn, __shfl_xor(mn, off));
    }
    if (t == 0){ sred[0] = mx; sred[1] = mn; }
  }
  __syncthreads();
  const float maxE1 = (c1 >= 0.f) ? c1*sred[0] : c1*sred[1];

  // ---- GAT1 column pass ----
  {
    const int j = lane;
    const float ecol = c2*xs[j];
    const float cb = lrelu(maxE1 + ecol);            // exact shift (lrelu monotone)
    const int w = j >> 5, bsel = j & 31;
    float sum = 0.f;
    const int i0 = h*64;
    #pragma unroll 8
    for (int k = 0; k < 64; ++k){
      int i = i0 + k;
      uint bit = (mk[i][w] >> bsel) & 1u;
      float e = lrelu(__fmaf_rn(c1, xs[i], ecol));
      float v = __expf(e - cb);
      sum += bit ? v : 0.f;
    }
    red2[h][j] = sum;
    if (h == 0) cs[j] = cb;
  }
  __syncthreads();
  if (t < 128) cr[t] = 1.f/(red2[0][t] + red2[1][t]);
  __syncthreads();
  // ---- GAT1 row pass: u_i ----
  {
    const int i = lane;
    const float erow = c1*xs[i];
    ull bits = ((ull)mk[i][2*h+1] << 32) | (ull)mk[i][2*h];
    float s = 0.f;
    const int j0 = h*64;
    #pragma unroll 8
    for (int k = 0; k < 64; ++k){
      int j = j0 + k;
      float xj = xs[j];
      float e = lrelu(__fmaf_rn(c2, xj, erow));
      float att = __expf(e - cs[j]) * cr[j];
      s += ((bits>>k)&1ull) ? att*xj : 0.f;
    }
    red2[h][i] = s;
  }
  __syncthreads();
  if (t < 128){
    float u = red2[0][t] + red2[1][t];
    uu[t] = u;
    eA[t] = (u >= 0.f ? pA : qA)*u;
    eB[t] = (u >= 0.f ? pB : qB)*u;
  }
  __syncthreads();
  if (t < 64){
    float mx = fmaxf(eA[t], eA[t+64]);
    #pragma unroll
    for (int off = 32; off; off >>= 1) mx = fmaxf(mx, __shfl_xor(mx, off));
    if (t == 0) sred[2] = mx;
  }
  __syncthreads();
  const float eAmax = sred[2];

  // ---- GAT2 column pass ----
  {
    const int j = lane;
    const float ecol = eB[j];
    const float cb = lrelu(eAmax + ecol);
    const int w = j >> 5, bsel = j & 31;
    float sum = 0.f;
    const int i0 = h*64;
    #pragma unroll 8
    for (int k = 0; k < 64; ++k){
      int i = i0 + k;
      uint bit = (mk[i][w] >> bsel) & 1u;
      float e = lrelu(eA[i] + ecol);
      float v = __expf(e - cb);
      sum += bit ? v : 0.f;
    }
    red2[h][j] = sum;
    if (h == 0) cs[j] = cb;
  }
  __syncthreads();
  if (t < 128) cr[t] = 1.f/(red2[0][t] + red2[1][t]);
  __syncthreads();
  // ---- GAT2 row pass: sp, sn ----
  {
    const int i = lane;
    const float erow = eA[i];
    ull bits = ((ull)mk[i][2*h+1] << 32) | (ull)mk[i][2*h];
    float sp = 0.f, sn = 0.f;
    const int j0 = h*64;
    #pragma unroll 8
    for (int k = 0; k < 64; ++k){
      int j = j0 + k;
      float uj = uu[j];
      float e = lrelu(erow + eB[j]);
      float att = __expf(e - cs[j]) * cr[j];
      att = ((bits>>k)&1ull) ? att : 0.f;
      sp = __fmaf_rn(att, fmaxf(uj, 0.f), sp);
      sn = __fmaf_rn(att, fminf(uj, 0.f), sn);
    }
    pool4[0][h][i] = sp; pool4[1][h][i] = sn;
  }
  __syncthreads();
  if (t < 128){
    float sp = pool4[0][0][t] + pool4[0][1][t];
    float sn = pool4[1][0][t] + pool4[1][1][t];
    float acc = 0.f;
    #pragma unroll
    for (int g = 0; g < 8; ++g) acc += reluf(__fmaf_rn(sp, consts[2+g], sn*consts[10+g]));
    hm[t] = 0.125f*acc;
  }
  __syncthreads();

  // ---- attention pooling (Weight/Wv are L2-resident: shared across all blocks) ----
  {
    const int n = lane;
    float a0=0.f, a1v=0.f, v0=0.f, v1=0.f;
    const int m0 = h*64;
    #pragma unroll 4
    for (int k = 0; k < 64; ++k){
      int m = m0 + k;
      float hmv = hm[m], tv = tim[m];
      float wg = Weight[(m<<7) + n], wvv = Wv[(m<<7) + n];
      a0 = __fmaf_rn(hmv, wg, a0); a1v = __fmaf_rn(tv, wg, a1v);
      v0 = __fmaf_rn(hmv, wvv, v0); v1 = __fmaf_rn(tv, wvv, v1);
    }
    pool4[0][h][n]=a0; pool4[1][h][n]=a1v; pool4[2][h][n]=v0; pool4[3][h][n]=v1;
  }
  __syncthreads();
  if (t < 128){
    cs[t] = pool4[0][0][t] + pool4[0][1][t];   // A0
    cr[t] = pool4[1][0][t] + pool4[1][1][t];   // A1
    eA[t] = pool4[2][0][t] + pool4[2][1][t];   // V0
    eB[t] = pool4[3][0][t] + pool4[3][1][t];   // V1
  } else if (t < 192){
    hq[t] = ip[b*64 + (t - 128)];
  }
  __syncthreads();
  if (t < 128){
    float a0 = cs[t], a1v = cr[t];
    float mx = fmaxf(a0, a1v);
    float e0 = __expf(a0 - mx), e1 = __expf(a1v - mx);
    float rs = 1.f/(e0 + e1);
    float r0, r1;
    if (t < 64){ r0 = eA[2*t];     r1 = eA[2*t+1];   }
    else       { r0 = eB[2*t-128]; r1 = eB[2*t-127]; }
    hq[t] = (reluf(r0)*e0 + reluf(r1)*e1)*rs;
  }
  __syncthreads();

  // ---- MHA (dim-1) + residual ----
  const float wq = mha_in_w[0], wk = mha_in_w[1], wv = mha_in_w[2];
  const float bq = mha_in_b[0], bk = mha_in_b[1], bv = mha_in_b[2];
  const float wo = mha_out_w[0], bo = mha_out_b[0];
  float hv_ = 0.f, qi = 0.f;
  if (t < 192){
    hv_ = hq[t];
    kv[t][0] = __fmaf_rn(hv_, wk, bk);
    kv[t][1] = __fmaf_rn(hv_, wv, bv);
    qi = __fmaf_rn(hv_, wq, bq);
  }
  __syncthreads();
  if (t < 64){
    float k0 = kv[t][0], k1 = kv[t+64][0], k2 = kv[t+128][0];
    float mx = fmaxf(fmaxf(k0, k1), k2);
    float mn = fminf(fminf(k0, k1), k2);
    #pragma unroll
    for (int off = 32; off; off >>= 1){
      mx = fmaxf(mx, __shfl_xor(mx, off));
      mn = fminf(mn, __shfl_xor(mn, off));
    }
    if (t == 0){ sred[3] = mx; sred[4] = mn; }
  }
  __syncthreads();
  if (t < 192){
    float mx = (qi >= 0.f) ? qi*sred[3] : qi*sred[4];   // exact max_j qi*k_j
    float den = 0.f, num = 0.f;
    #pragma unroll 8
    for (int j = 0; j < 192; ++j){
      float e = __expf(__fmaf_rn(qi, kv[j][0], -mx));
      den += e; num = __fmaf_rn(e, kv[j][1], num);
    }
    h2s[t] = __fmaf_rn(num/den, wo, bo) + hv_;
  }
  __syncthreads();
  // ---- fl1: 192 -> 128, relu ----
  if (t < 128){
    float acc = fl1_b[t];
    #pragma unroll 8
    for (int i = 0; i < 192; ++i) acc = __fmaf_rn(h2s[i], fl1_w[i*128 + t], acc);
    red2[0][t] = reluf(acc);
  }
  __syncthreads();
  // ---- fl2: 128 -> 32, tanh (4-way split over threads) ----
  if (t < 128){
    const int n = t & 31, seg = t >> 5;
    float p = 0.f;
    #pragma unroll 8
    for (int k = 0; k < 32; ++k){
      int i = seg*32 + k;
      p = __fmaf_rn(red2[0][i], fl2_w[i*32 + n], p);
    }
    pool4[0][0][t] = p;
  }
  __syncthreads();
  if (t < 32){
    float s = pool4[0][0][t] + pool4[0][0][t+32] + pool4[0][0][t+64] + pool4[0][0][t+96] + fl2_b[t];
    o2s[t] = tanh_fast(s);
  }
  __syncthreads();
  // ---- fl3: 32 -> 1, relu ----
  if (t < 64){
    float p = (t < 32) ? o2s[t]*fl3_w[t] : 0.f;
    #pragma unroll
    for (int off = 32; off; off >>= 1) p += __shfl_xor(p, off);
    if (t == 0) out[b] = reluf(p + fl3_b[0]);
  }
}

extern "C" void kernel_launch(void* const* d_in, const int* in_sizes, int n_in,
                              void* d_out, int out_size, void* d_ws, size_t ws_size,
                              hipStream_t stream) {
  const int*   adj    = (const int*)  d_in[0];
  const float* feat   = (const float*)d_in[1];
  const float* timei  = (const float*)d_in[2];
  const float* ipop   = (const float*)d_in[3];
  const float* W1     = (const float*)d_in[4];
  const float* a1     = (const float*)d_in[5];
  const float* W2     = (const float*)d_in[6];
  const float* a2     = (const float*)d_in[7];
  const float* Weight = (const float*)d_in[8];
  const float* Wv     = (const float*)d_in[9];
  const float* wih0   = (const float*)d_in[10];
  const float* whh0   = (const float*)d_in[11];
  const float* bih0   = (const float*)d_in[12];
  const float* bhh0   = (const float*)d_in[13];
  const float* wih1   = (const float*)d_in[14];
  const float* whh1   = (const float*)d_in[15];
  const float* bih1   = (const float*)d_in[16];
  const float* bhh1   = (const float*)d_in[17];
  const float* mha_in_w  = (const float*)d_in[18];
  const float* mha_in_b  = (const float*)d_in[19];
  const float* mha_out_w = (const float*)d_in[20];
  const float* mha_out_b = (const float*)d_in[21];
  const float* fl1_w = (const float*)d_in[22];
  const float* fl1_b = (const float*)d_in[23];
  const float* fl2_w = (const float*)d_in[24];
  const float* fl2_b = (const float*)d_in[25];
  const float* fl3_w = (const float*)d_in[26];
  const float* fl3_b = (const float*)d_in[27];

  uint*  packed = (uint*)d_ws;                     // 262144 words = 1 MB
  float* consts = (float*)d_ws + 262144;           // 32 floats
  float* ip     = (float*)d_ws + 262144 + 32;      // 512*64 floats

  prep_kernel<<<1033, 256, 0, stream>>>(adj, packed, W1, a1, W2, a2, consts,
                                        ipop, wih0, whh0, bih0, bhh0,
                                        wih1, whh1, bih1, bhh1, ip);
  gat_head_kernel<<<512, 256, 0, stream>>>(packed, feat, timei, Weight, Wv, consts, ip,
                                           mha_in_w, mha_in_b, mha_out_w, mha_out_b,
                                           fl1_w, fl1_b, fl2_w, fl2_b, fl3_w, fl3_b,
                                           (float*)d_out);
}